// Round 4
// baseline (284.041 us; speedup 1.0000x reference)
//
#include <hip/hip_runtime.h>
#include <hip/hip_bf16.h>
#include <cstdint>
#include <cstddef>

#define BDIM 32768
#define IDIM 512
#define ODIM 512
#define KDIM 1024   // I+O
#define NDIM 2048   // 4*O

typedef __attribute__((ext_vector_type(8))) __bf16 bf16x8;
typedef __attribute__((ext_vector_type(4))) float f32x4;
typedef __attribute__((ext_vector_type(8))) unsigned short u16x8;

__device__ __forceinline__ unsigned short f2bf(float x) {
  union { float f; uint32_t u; } v; v.f = x;
  uint32_t r = v.u + 0x7FFFu + ((v.u >> 16) & 1u);  // RNE
  return (unsigned short)(r >> 16);
}

__device__ __forceinline__ float bf2f(unsigned short s) {
  union { uint32_t u; float f; } v; v.u = ((uint32_t)s) << 16;
  return v.f;
}

// ---------------- pack kernels: f32 -> bf16 ----------------

__global__ __launch_bounds__(256) void pack_a_kernel(const float* __restrict__ in,
                                                     const float* __restrict__ h,
                                                     unsigned short* __restrict__ A) {
  size_t t = (size_t)blockIdx.x * 256 + threadIdx.x;
  size_t e = t * 8;
  size_t b = e >> 10;
  int col = (int)(e & 1023);
  const float* src = (col < IDIM) ? (in + b * IDIM + col)
                                  : (h + b * ODIM + (col - IDIM));
  float4 v0 = ((const float4*)src)[0];
  float4 v1 = ((const float4*)src)[1];
  u16x8 r;
  r[0] = f2bf(v0.x); r[1] = f2bf(v0.y); r[2] = f2bf(v0.z); r[3] = f2bf(v0.w);
  r[4] = f2bf(v1.x); r[5] = f2bf(v1.y); r[6] = f2bf(v1.z); r[7] = f2bf(v1.w);
  *(u16x8*)(A + e) = r;
}

__global__ __launch_bounds__(256) void pack_w_kernel(const float* __restrict__ Wsrc,
                                                     unsigned short* __restrict__ Wb) {
  size_t t = (size_t)blockIdx.x * 256 + threadIdx.x;
  size_t e = t * 8;
  float4 v0 = ((const float4*)(Wsrc + e))[0];
  float4 v1 = ((const float4*)(Wsrc + e))[1];
  u16x8 r;
  r[0] = f2bf(v0.x); r[1] = f2bf(v0.y); r[2] = f2bf(v0.z); r[3] = f2bf(v0.w);
  r[4] = f2bf(v1.x); r[5] = f2bf(v1.y); r[6] = f2bf(v1.z); r[7] = f2bf(v1.w);
  *(u16x8*)(Wb + e) = r;
}

// ---------------- GEMM: 256x256 tile, BK=64, fragment-ordered LDS ----------------
// 8 waves (2M x 4N), per-wave 128x64 output = acc[8][4] f32x4.
// LDS layout (per 64KB buffer): A region 32KB = 32 frags x 1KB, frag id =
// s*16 + mi (s = k-half 0/1, mi = 16-row m-frag 0..15); B region at +32768,
// same with n-frags. Fragment = 64 lanes x 16B contiguous (lane l holds
// row (l&15), k-chunk (l>>4)): ds_read_b128 at base+lane*16 is perfectly
// linear -> zero bank conflicts by construction. Staging: wave w, round j
// stages frag (j*8+w) with per-lane pre-permuted global source.
// 4 phases per K-tile: {ds_read 8|4, 2x global_load_lds, BAR, lgkm0,
// setprio, 16 MFMA, setprio, [vmcnt(4) at half-tile boundaries], BAR}.

#define GB 65536

#define BAR() do { asm volatile("" ::: "memory"); __builtin_amdgcn_s_barrier(); asm volatile("" ::: "memory"); } while (0)
#define VMW(n) asm volatile("s_waitcnt vmcnt(" #n ")" ::: "memory")
#define LGKM0() do { asm volatile("s_waitcnt lgkmcnt(0)" ::: "memory"); __builtin_amdgcn_sched_barrier(0); } while (0)

__device__ __forceinline__ void gll16(const unsigned short* src, char* ldsdst) {
  __builtin_amdgcn_global_load_lds(
      (const __attribute__((address_space(1))) void*)src,
      (__attribute__((address_space(3))) void*)ldsdst, 16, 0, 0);
}

__device__ __forceinline__ void mf16(const bf16x8 (&a)[4], const bf16x8 (&q)[4],
                                     f32x4 (&acc)[8][4], int mb) {
#pragma unroll
  for (int i = 0; i < 4; ++i)
#pragma unroll
    for (int j = 0; j < 4; ++j)
      acc[mb + i][j] = __builtin_amdgcn_mfma_f32_16x16x32_bf16(a[i], q[j], acc[mb + i][j], 0, 0, 0);
}

template<int BUF, bool STG, bool FINAL>
__device__ __forceinline__ void ktile(char* aR, char* bR, char* stA, char* stB,
                                      const unsigned short* pA0, const unsigned short* pA1,
                                      const unsigned short* pB0, const unsigned short* pB1,
                                      int stOff, f32x4 (&acc)[8][4]) {
  bf16x8 af[4], qf[4];
  // ---- phase 1: A mi0-3 s0 + B nj0-3 s0 ; stage next-tile A s0
#pragma unroll
  for (int i = 0; i < 4; ++i) af[i] = *(const bf16x8*)(aR + i * 1024);
#pragma unroll
  for (int j = 0; j < 4; ++j) qf[j] = *(const bf16x8*)(bR + j * 1024);
  if (STG) { gll16(pA0, stA + stOff); gll16(pA1, stA + 8192 + stOff); }
  BAR(); LGKM0();
  __builtin_amdgcn_s_setprio(1);
  mf16(af, qf, acc, 0);
  __builtin_amdgcn_s_setprio(0);
  __builtin_amdgcn_sched_barrier(0);
  BAR();
  // ---- phase 2: A mi4-7 s0 ; stage next-tile B s0 ; guard s1 reads
#pragma unroll
  for (int i = 0; i < 4; ++i) af[i] = *(const bf16x8*)(aR + (4 + i) * 1024);
  if (STG) { gll16(pB0, stB + stOff); gll16(pB1, stB + 8192 + stOff); }
  BAR(); LGKM0();
  __builtin_amdgcn_s_setprio(1);
  mf16(af, qf, acc, 4);
  __builtin_amdgcn_s_setprio(0);
  __builtin_amdgcn_sched_barrier(0);
  if (FINAL) VMW(0); else VMW(4);
  BAR();
  // ---- phase 3: A mi0-3 s1 + B nj0-3 s1 ; stage next-tile A s1
#pragma unroll
  for (int i = 0; i < 4; ++i) af[i] = *(const bf16x8*)(aR + 16384 + i * 1024);
#pragma unroll
  for (int j = 0; j < 4; ++j) qf[j] = *(const bf16x8*)(bR + 16384 + j * 1024);
  if (STG) { gll16(pA0 + 32, stA + 16384 + stOff); gll16(pA1 + 32, stA + 24576 + stOff); }
  BAR(); LGKM0();
  __builtin_amdgcn_s_setprio(1);
  mf16(af, qf, acc, 0);
  __builtin_amdgcn_s_setprio(0);
  __builtin_amdgcn_sched_barrier(0);
  BAR();
  // ---- phase 4: A mi4-7 s1 ; stage next-tile B s1 ; guard next-tile s0 reads
#pragma unroll
  for (int i = 0; i < 4; ++i) af[i] = *(const bf16x8*)(aR + 16384 + (4 + i) * 1024);
  if (STG) { gll16(pB0 + 32, stB + 16384 + stOff); gll16(pB1 + 32, stB + 24576 + stOff); }
  BAR(); LGKM0();
  __builtin_amdgcn_s_setprio(1);
  mf16(af, qf, acc, 4);
  __builtin_amdgcn_s_setprio(0);
  __builtin_amdgcn_sched_barrier(0);
  if (!FINAL) VMW(4);
  BAR();
}

__global__ __launch_bounds__(512, 2) void gemm_kernel(const unsigned short* __restrict__ A,
                                                      const unsigned short* __restrict__ Bt,
                                                      unsigned short* __restrict__ Cz) {
  extern __shared__ char smem[];
  const int tid = threadIdx.x;
  const int w = tid >> 6;
  const int lane = tid & 63;

  // XCD swizzle: each XCD gets a 16-mtile x 8-ntile chunk (B panel L2-resident)
  const int bid = blockIdx.x;                       // 0..1023
  const int swz = (bid & 7) * 128 + (bid >> 3);
  const int m0 = (swz >> 3) * 256;
  const int n0 = (swz & 7) * 256;

  const int wm = (w >> 2) * 128;   // 2 M-wave-rows
  const int wn = (w & 3) * 64;     // 4 N-wave-cols
  const int lrow = lane & 15;
  const int lk = (lane >> 4) * 8;

  // fragment read bases (linear, conflict-free)
  char* aR0 = smem + (w >> 2) * 8192 + lane * 16;
  char* bR0 = smem + 32768 + (w & 3) * 4096 + lane * 16;
  char* aR1 = aR0 + GB;
  char* bR1 = bR0 + GB;
  const int stOff = w * 1024 + lane * 16;

  // staging sources: wave w stages A-frags {w, 8+w}, B-frags {w, 8+w}
  const unsigned short* pA0 = A  + (size_t)(m0 + w * 16       + lrow) * KDIM + lk;
  const unsigned short* pA1 = A  + (size_t)(m0 + (8 + w) * 16 + lrow) * KDIM + lk;
  const unsigned short* pB0 = Bt + (size_t)(n0 + w * 16       + lrow) * KDIM + lk;
  const unsigned short* pB1 = Bt + (size_t)(n0 + (8 + w) * 16 + lrow) * KDIM + lk;

  f32x4 acc[8][4] = {};

  // prologue: stage tile 0 into buffer 0 (s0 half first, then s1 half)
  gll16(pA0,      smem + stOff);
  gll16(pA1,      smem + 8192 + stOff);
  gll16(pB0,      smem + 32768 + stOff);
  gll16(pB1,      smem + 40960 + stOff);
  gll16(pA0 + 32, smem + 16384 + stOff);
  gll16(pA1 + 32, smem + 24576 + stOff);
  gll16(pB0 + 32, smem + 49152 + stOff);
  gll16(pB1 + 32, smem + 57344 + stOff);
  VMW(4);
  BAR();
  pA0 += 64; pA1 += 64; pB0 += 64; pB1 += 64;

  // main loop: 16 K-tiles, double-buffered, stage t+1 while computing t
  for (int tt = 0; tt < 7; ++tt) {
    ktile<0, true, false>(aR0, bR0, smem + GB, smem + GB + 32768, pA0, pA1, pB0, pB1, stOff, acc);
    pA0 += 64; pA1 += 64; pB0 += 64; pB1 += 64;
    ktile<1, true, false>(aR1, bR1, smem, smem + 32768, pA0, pA1, pB0, pB1, stOff, acc);
    pA0 += 64; pA1 += 64; pB0 += 64; pB1 += 64;
  }
  ktile<0, true, false>(aR0, bR0, smem + GB, smem + GB + 32768, pA0, pA1, pB0, pB1, stOff, acc);  // t14 stages t15
  ktile<1, false, true>(aR1, bR1, smem, smem + 32768, pA0, pA1, pB0, pB1, stOff, acc);            // t15

  // epilogue: C/D layout col = lane&15, row = (lane>>4)*4 + r
#pragma unroll
  for (int mi = 0; mi < 8; ++mi) {
#pragma unroll
    for (int ni = 0; ni < 4; ++ni) {
#pragma unroll
      for (int r = 0; r < 4; ++r) {
        const int row = m0 + wm + mi * 16 + (lane >> 4) * 4 + r;
        const int col = n0 + wn + ni * 16 + lrow;
        Cz[(size_t)row * NDIM + col] = f2bf(acc[mi][ni][r]);
      }
    }
  }
}

// ---------------- LayerNorm + gates ----------------

__global__ __launch_bounds__(256) void ln_gate_kernel(const unsigned short* __restrict__ z,
                                                      const float* __restrict__ c,
                                                      const float* __restrict__ gamma,
                                                      const float* __restrict__ beta,
                                                      float* __restrict__ out) {
  __shared__ float rowbuf[4][NDIM];  // 32 KB
  const int wave = threadIdx.x >> 6;
  const int lane = threadIdx.x & 63;
  const int row = blockIdx.x * 4 + wave;
  const unsigned short* zr = z + (size_t)row * NDIM;

  float s = 0.f, ss = 0.f;
#pragma unroll
  for (int j = 0; j < 4; ++j) {
    const int chunk = j * 64 + lane;
    u16x8 v = *(const u16x8*)(zr + chunk * 8);
    float f[8];
#pragma unroll
    for (int i2 = 0; i2 < 8; ++i2) {
      f[i2] = bf2f(v[i2]);
      s += f[i2];
      ss += f[i2] * f[i2];
    }
    float4* dst = (float4*)&rowbuf[wave][chunk * 8];
    dst[0] = make_float4(f[0], f[1], f[2], f[3]);
    dst[1] = make_float4(f[4], f[5], f[6], f[7]);
  }
#pragma unroll
  for (int off = 32; off > 0; off >>= 1) {
    s += __shfl_xor(s, off, 64);
    ss += __shfl_xor(ss, off, 64);
  }
  const float mean = s * (1.f / (float)NDIM);
  const float var = ss * (1.f / (float)NDIM) - mean * mean;
  const float inv = rsqrtf(var + 1e-5f);

  float* out_o = out + (size_t)row * ODIM;
  float* out_c = out + (size_t)BDIM * ODIM + (size_t)row * ODIM;
  const float* crow = c + (size_t)row * ODIM;

#pragma unroll
  for (int j = 0; j < 8; ++j) {
    const int o = j * 64 + lane;
    float zn[4];
#pragma unroll
    for (int g = 0; g < 4; ++g) {
      float v = (rowbuf[wave][g * ODIM + o] - mean) * inv;
      zn[g] = v * gamma[g * ODIM + o] + beta[g * ODIM + o];
    }
    const float fg = 1.f / (1.f + expf(-zn[0]));
    const float ig = 1.f / (1.f + expf(-zn[1]));
    const float og = 1.f / (1.f + expf(-zn[2]));
    const float x = zn[3];
    const float hs = 0.5f * x * (1.f + erff(x * 0.70710678118654752f));
    const float cc = fg * crow[o] + ig * hs;
    out_c[o] = cc;
    out_o[o] = og * cc;
  }
}

// ---------------- launch ----------------

extern "C" void kernel_launch(void* const* d_in, const int* in_sizes, int n_in,
                              void* d_out, int out_size, void* d_ws, size_t ws_size,
                              hipStream_t stream) {
  const float* input = (const float*)d_in[0];
  const float* h     = (const float*)d_in[1];
  const float* c     = (const float*)d_in[2];
  const float* W     = (const float*)d_in[3];
  const float* gamma = (const float*)d_in[4];
  const float* beta  = (const float*)d_in[5];

  unsigned short* A  = (unsigned short*)d_ws;                 // [32768,1024] bf16
  unsigned short* Wb = A + (size_t)BDIM * KDIM;               // [2048,1024] bf16
  unsigned short* z  = Wb + (size_t)NDIM * KDIM;              // [32768,2048] bf16
  float* out = (float*)d_out;

  hipFuncSetAttribute((const void*)gemm_kernel,
                      hipFuncAttributeMaxDynamicSharedMemorySize, 131072);

  pack_a_kernel<<<(BDIM * KDIM / 8) / 256, 256, 0, stream>>>(input, h, A);
  pack_w_kernel<<<(NDIM * KDIM / 8) / 256, 256, 0, stream>>>(W, Wb);
  gemm_kernel<<<dim3((BDIM / 256) * (NDIM / 256)), 512, 131072, stream>>>(A, Wb, z);
  ln_gate_kernel<<<BDIM / 4, 256, 0, stream>>>(z, c, gamma, beta, out);
}

// Round 5
// 283.912 us; speedup vs baseline: 1.0005x; 1.0005x over previous
//
#include <hip/hip_runtime.h>
#include <hip/hip_bf16.h>
#include <cstdint>
#include <cstddef>

#define BDIM 32768
#define IDIM 512
#define ODIM 512
#define KDIM 1024   // I+O
#define NDIM 2048   // 4*O

typedef __attribute__((ext_vector_type(8))) __bf16 bf16x8;
typedef __attribute__((ext_vector_type(4))) float f32x4;
typedef __attribute__((ext_vector_type(8))) unsigned short u16x8;

__device__ __forceinline__ unsigned short f2bf(float x) {
  union { float f; uint32_t u; } v; v.f = x;
  uint32_t r = v.u + 0x7FFFu + ((v.u >> 16) & 1u);  // RNE
  return (unsigned short)(r >> 16);
}

__device__ __forceinline__ float bf2f(unsigned short s) {
  union { uint32_t u; float f; } v; v.u = ((uint32_t)s) << 16;
  return v.f;
}

// ---------------- pack kernels: f32 -> bf16 ----------------

__global__ __launch_bounds__(256) void pack_a_kernel(const float* __restrict__ in,
                                                     const float* __restrict__ h,
                                                     unsigned short* __restrict__ A) {
  size_t t = (size_t)blockIdx.x * 256 + threadIdx.x;
  size_t e = t * 8;
  size_t b = e >> 10;
  int col = (int)(e & 1023);
  const float* src = (col < IDIM) ? (in + b * IDIM + col)
                                  : (h + b * ODIM + (col - IDIM));
  float4 v0 = ((const float4*)src)[0];
  float4 v1 = ((const float4*)src)[1];
  u16x8 r;
  r[0] = f2bf(v0.x); r[1] = f2bf(v0.y); r[2] = f2bf(v0.z); r[3] = f2bf(v0.w);
  r[4] = f2bf(v1.x); r[5] = f2bf(v1.y); r[6] = f2bf(v1.z); r[7] = f2bf(v1.w);
  *(u16x8*)(A + e) = r;
}

__global__ __launch_bounds__(256) void pack_w_kernel(const float* __restrict__ Wsrc,
                                                     unsigned short* __restrict__ Wb) {
  size_t t = (size_t)blockIdx.x * 256 + threadIdx.x;
  size_t e = t * 8;
  float4 v0 = ((const float4*)(Wsrc + e))[0];
  float4 v1 = ((const float4*)(Wsrc + e))[1];
  u16x8 r;
  r[0] = f2bf(v0.x); r[1] = f2bf(v0.y); r[2] = f2bf(v0.z); r[3] = f2bf(v0.w);
  r[4] = f2bf(v1.x); r[5] = f2bf(v1.y); r[6] = f2bf(v1.z); r[7] = f2bf(v1.w);
  *(u16x8*)(Wb + e) = r;
}

// ---------------- GEMM: 256x256 tile, BK=32, ring-4, fragment-ordered LDS ----------------
// 8 waves (2M x 4N), per-wave 128x64 output = acc[8][4] f32x4.
// Ring of 4 x 32KB buffers (128KB dynamic LDS). Per buffer: A = 16 frags x 1KB
// (frag mi covers rows mi*16..+15), B at +16384 same. Fragment = 64 lanes x 16B
// contiguous (lane l: row l&15, k-chunk l>>4) -> ds_read_b128 at base+lane*16
// is linear => ZERO bank conflicts (verified R4). Staging: wave w stages
// A-frags {w,w+8}, B-frags {w,w+8} of tile t+3 (per-lane pre-permuted global
// source; wave-uniform LDS dest). ONE barrier per K-tile: {VMW(8); s_barrier}.
// Safety: each wave's ds_reads of tile t are consumed (lgkm-waited) by its
// MFMAs before it reaches tile t+1's barrier, so staging into buffer (t)&3
// during tile t+1 cannot overwrite unread data. vmcnt FIFO: 4 loads/tile,
// steady 12 outstanding, VMW(8) retires exactly tile t's 4; taper 8->8->4->0.

#define BUFSZ 32768

#define BAR() do { asm volatile("" ::: "memory"); __builtin_amdgcn_s_barrier(); asm volatile("" ::: "memory"); } while (0)
#define VMW(n) asm volatile("s_waitcnt vmcnt(" #n ")" ::: "memory")

__device__ __forceinline__ void gll16(const unsigned short* src, char* ldsdst) {
  __builtin_amdgcn_global_load_lds(
      (const __attribute__((address_space(1))) void*)src,
      (__attribute__((address_space(3))) void*)ldsdst, 16, 0, 0);
}

template<int BUF, int VM, bool STG>
__device__ __forceinline__ void ktile(char* smem, char* aR, char* bR,
                                      const unsigned short* pA0, const unsigned short* pA1,
                                      const unsigned short* pB0, const unsigned short* pB1,
                                      int stOff, f32x4 (&acc)[8][4]) {
  constexpr int CB = BUF * BUFSZ;
  constexpr int DB = ((BUF + 3) & 3) * BUFSZ;

  if (VM == 8)      VMW(8);
  else if (VM == 4) VMW(4);
  else              VMW(0);
  BAR();

  bf16x8 af[8], qf[4];
#pragma unroll
  for (int i = 0; i < 8; ++i) af[i] = *(const bf16x8*)(aR + CB + i * 1024);
#pragma unroll
  for (int j = 0; j < 4; ++j) qf[j] = *(const bf16x8*)(bR + CB + j * 1024);
  if (STG) {
    gll16(pA0, smem + DB + stOff);           // A frag w
    gll16(pA1, smem + DB + 8192 + stOff);    // A frag w+8
    gll16(pB0, smem + DB + 16384 + stOff);   // B frag w
    gll16(pB1, smem + DB + 24576 + stOff);   // B frag w+8
  }
  __builtin_amdgcn_sched_barrier(0);         // loads issued before MFMA cluster
  __builtin_amdgcn_s_setprio(1);
#pragma unroll
  for (int i = 0; i < 8; ++i)
#pragma unroll
    for (int j = 0; j < 4; ++j)
      acc[i][j] = __builtin_amdgcn_mfma_f32_16x16x32_bf16(af[i], qf[j], acc[i][j], 0, 0, 0);
  __builtin_amdgcn_s_setprio(0);
}

__global__ __launch_bounds__(512, 2) void gemm_kernel(const unsigned short* __restrict__ A,
                                                      const unsigned short* __restrict__ Bt,
                                                      unsigned short* __restrict__ Cz) {
  extern __shared__ char smem[];
  const int tid = threadIdx.x;
  const int w = tid >> 6;
  const int lane = tid & 63;

  // XCD swizzle: each XCD gets a 16-mtile x 8-ntile chunk (B panel L2-resident)
  const int bid = blockIdx.x;                       // 0..1023
  const int swz = (bid & 7) * 128 + (bid >> 3);
  const int m0 = (swz >> 3) * 256;
  const int n0 = (swz & 7) * 256;

  const int wm = (w >> 2) * 128;   // 2 M-wave-rows
  const int wn = (w & 3) * 64;     // 4 N-wave-cols
  const int lrow = lane & 15;
  const int lk = (lane >> 4) * 8;

  // fragment read bases (linear within frag -> conflict-free)
  char* aR = smem + (w >> 2) * 8192 + lane * 16;           // A frags (w>>2)*8 + 0..7
  char* bR = smem + 16384 + (w & 3) * 4096 + lane * 16;    // B frags (w&3)*4 + 0..3
  const int stOff = w * 1024 + lane * 16;                  // wave-uniform (lane0) dest

  // staging sources: wave w stages A-frags {w, w+8}, B-frags {w, w+8}
  const unsigned short* pA0 = A  + (size_t)(m0 + w * 16       + lrow) * KDIM + lk;
  const unsigned short* pA1 = A  + (size_t)(m0 + (8 + w) * 16 + lrow) * KDIM + lk;
  const unsigned short* pB0 = Bt + (size_t)(n0 + w * 16       + lrow) * KDIM + lk;
  const unsigned short* pB1 = Bt + (size_t)(n0 + (8 + w) * 16 + lrow) * KDIM + lk;

  f32x4 acc[8][4] = {};

  // prologue: stage tiles 0,1,2 into buffers 0,1,2 (FIFO order by tile)
#pragma unroll
  for (int t = 0; t < 3; ++t) {
    gll16(pA0 + t * 32, smem + t * BUFSZ + stOff);
    gll16(pA1 + t * 32, smem + t * BUFSZ + 8192 + stOff);
    gll16(pB0 + t * 32, smem + t * BUFSZ + 16384 + stOff);
    gll16(pB1 + t * 32, smem + t * BUFSZ + 24576 + stOff);
  }
  // pointers now used for staging tile t+3 during tile t: k = 32*(t+3)
  pA0 += 96; pA1 += 96; pB0 += 96; pB1 += 96;

  // main loop: 32 K-tiles; tile t computes buf t&3, stages tile t+3 into buf (t+3)&3
  for (int tt = 0; tt < 7; ++tt) {
    ktile<0, 8, true>(smem, aR, bR, pA0, pA1, pB0, pB1, stOff, acc);
    pA0 += 32; pA1 += 32; pB0 += 32; pB1 += 32;
    ktile<1, 8, true>(smem, aR, bR, pA0, pA1, pB0, pB1, stOff, acc);
    pA0 += 32; pA1 += 32; pB0 += 32; pB1 += 32;
    ktile<2, 8, true>(smem, aR, bR, pA0, pA1, pB0, pB1, stOff, acc);
    pA0 += 32; pA1 += 32; pB0 += 32; pB1 += 32;
    ktile<3, 8, true>(smem, aR, bR, pA0, pA1, pB0, pB1, stOff, acc);
    pA0 += 32; pA1 += 32; pB0 += 32; pB1 += 32;
  }
  ktile<0, 8, true >(smem, aR, bR, pA0, pA1, pB0, pB1, stOff, acc);  // t28 stages t31
  ktile<1, 8, false>(smem, aR, bR, pA0, pA1, pB0, pB1, stOff, acc);  // t29
  ktile<2, 4, false>(smem, aR, bR, pA0, pA1, pB0, pB1, stOff, acc);  // t30
  ktile<3, 0, false>(smem, aR, bR, pA0, pA1, pB0, pB1, stOff, acc);  // t31

  // epilogue: C/D layout col = lane&15, row = (lane>>4)*4 + r
#pragma unroll
  for (int mi = 0; mi < 8; ++mi) {
#pragma unroll
    for (int ni = 0; ni < 4; ++ni) {
#pragma unroll
      for (int r = 0; r < 4; ++r) {
        const int row = m0 + wm + mi * 16 + (lane >> 4) * 4 + r;
        const int col = n0 + wn + ni * 16 + lrow;
        Cz[(size_t)row * NDIM + col] = f2bf(acc[mi][ni][r]);
      }
    }
  }
}

// ---------------- LayerNorm + gates ----------------

__global__ __launch_bounds__(256) void ln_gate_kernel(const unsigned short* __restrict__ z,
                                                      const float* __restrict__ c,
                                                      const float* __restrict__ gamma,
                                                      const float* __restrict__ beta,
                                                      float* __restrict__ out) {
  __shared__ float rowbuf[4][NDIM];  // 32 KB
  const int wave = threadIdx.x >> 6;
  const int lane = threadIdx.x & 63;
  const int row = blockIdx.x * 4 + wave;
  const unsigned short* zr = z + (size_t)row * NDIM;

  float s = 0.f, ss = 0.f;
#pragma unroll
  for (int j = 0; j < 4; ++j) {
    const int chunk = j * 64 + lane;
    u16x8 v = *(const u16x8*)(zr + chunk * 8);
    float f[8];
#pragma unroll
    for (int i2 = 0; i2 < 8; ++i2) {
      f[i2] = bf2f(v[i2]);
      s += f[i2];
      ss += f[i2] * f[i2];
    }
    float4* dst = (float4*)&rowbuf[wave][chunk * 8];
    dst[0] = make_float4(f[0], f[1], f[2], f[3]);
    dst[1] = make_float4(f[4], f[5], f[6], f[7]);
  }
#pragma unroll
  for (int off = 32; off > 0; off >>= 1) {
    s += __shfl_xor(s, off, 64);
    ss += __shfl_xor(ss, off, 64);
  }
  const float mean = s * (1.f / (float)NDIM);
  const float var = ss * (1.f / (float)NDIM) - mean * mean;
  const float inv = rsqrtf(var + 1e-5f);

  float* out_o = out + (size_t)row * ODIM;
  float* out_c = out + (size_t)BDIM * ODIM + (size_t)row * ODIM;
  const float* crow = c + (size_t)row * ODIM;

#pragma unroll
  for (int j = 0; j < 8; ++j) {
    const int o = j * 64 + lane;
    float zn[4];
#pragma unroll
    for (int g = 0; g < 4; ++g) {
      float v = (rowbuf[wave][g * ODIM + o] - mean) * inv;
      zn[g] = v * gamma[g * ODIM + o] + beta[g * ODIM + o];
    }
    const float fg = 1.f / (1.f + expf(-zn[0]));
    const float ig = 1.f / (1.f + expf(-zn[1]));
    const float og = 1.f / (1.f + expf(-zn[2]));
    const float x = zn[3];
    const float hs = 0.5f * x * (1.f + erff(x * 0.70710678118654752f));
    const float cc = fg * crow[o] + ig * hs;
    out_c[o] = cc;
    out_o[o] = og * cc;
  }
}

// ---------------- launch ----------------

extern "C" void kernel_launch(void* const* d_in, const int* in_sizes, int n_in,
                              void* d_out, int out_size, void* d_ws, size_t ws_size,
                              hipStream_t stream) {
  const float* input = (const float*)d_in[0];
  const float* h     = (const float*)d_in[1];
  const float* c     = (const float*)d_in[2];
  const float* W     = (const float*)d_in[3];
  const float* gamma = (const float*)d_in[4];
  const float* beta  = (const float*)d_in[5];

  unsigned short* A  = (unsigned short*)d_ws;                 // [32768,1024] bf16
  unsigned short* Wb = A + (size_t)BDIM * KDIM;               // [2048,1024] bf16
  unsigned short* z  = Wb + (size_t)NDIM * KDIM;              // [32768,2048] bf16
  float* out = (float*)d_out;

  hipFuncSetAttribute((const void*)gemm_kernel,
                      hipFuncAttributeMaxDynamicSharedMemorySize, 131072);

  pack_a_kernel<<<(BDIM * KDIM / 8) / 256, 256, 0, stream>>>(input, h, A);
  pack_w_kernel<<<(NDIM * KDIM / 8) / 256, 256, 0, stream>>>(W, Wb);
  gemm_kernel<<<dim3((BDIM / 256) * (NDIM / 256)), 512, 131072, stream>>>(A, Wb, z);
  ln_gate_kernel<<<BDIM / 4, 256, 0, stream>>>(z, c, gamma, beta, out);
}